// Round 1
// baseline (103.759 us; speedup 1.0000x reference)
//
#include <hip/hip_runtime.h>
#include <stdint.h>

// ---------------------------------------------------------------------------
// WindowedAttn: x(2,2048,1024) f32 -> QKV proj -> windowed causal attn (W=256)
// -> out proj. bf16 MFMA pipeline, f32 in/out.
// ---------------------------------------------------------------------------

typedef __attribute__((ext_vector_type(8))) short bf16x8;     // 8 bf16 (4 VGPR)
typedef __attribute__((ext_vector_type(4))) float f32x4;      // MFMA C/D
typedef __attribute__((ext_vector_type(4))) unsigned int u32x4;
typedef __attribute__((ext_vector_type(4))) unsigned short u16x4;

#define DEV static __device__ __forceinline__

DEV unsigned short f2bf(float f) {            // f32 -> bf16 RNE
  unsigned int u = __builtin_bit_cast(unsigned int, f);
  u += 0x7fffu + ((u >> 16) & 1u);
  return (unsigned short)(u >> 16);
}

DEV void gload_lds16(const void* g, void* l) { // 16B global -> LDS direct
  __builtin_amdgcn_global_load_lds((const __attribute__((address_space(1))) void*)g,
                                   (__attribute__((address_space(3))) void*)l,
                                   16, 0, 0);
}

// --------------------------- fp32 -> bf16 ----------------------------------
__global__ __launch_bounds__(256) void k_f32_to_bf16(const float* __restrict__ in,
                                                     unsigned short* __restrict__ out,
                                                     int n4) {
  int i = blockIdx.x * 256 + threadIdx.x;
  if (i >= n4) return;
  f32x4 v = ((const f32x4*)in)[i];
  u16x4 o;
  o[0] = f2bf(v[0]); o[1] = f2bf(v[1]); o[2] = f2bf(v[2]); o[3] = f2bf(v[3]);
  ((u16x4*)out)[i] = o;
}

// ------------------- transpose + convert: out[n][k] = in[k][n] -------------
__global__ __launch_bounds__(256) void k_transpose_w(const float* __restrict__ in,
                                                     unsigned short* __restrict__ out,
                                                     int K, int N) {
  __shared__ float t[32][33];
  const int tx = threadIdx.x, ty = threadIdx.y;
  const int n0 = blockIdx.x * 32, k0 = blockIdx.y * 32;
#pragma unroll
  for (int i = 0; i < 4; ++i)
    t[ty + i * 8][tx] = in[(size_t)(k0 + ty + i * 8) * N + n0 + tx];
  __syncthreads();
#pragma unroll
  for (int i = 0; i < 4; ++i)
    out[(size_t)(n0 + ty + i * 8) * K + k0 + tx] = f2bf(t[tx][ty + i * 8]);
}

// --------------------------- bf16 GEMM -------------------------------------
// C[M][N] = A[M][K] @ Bt[N][K]^T + bias.  128x128 tile, 4 waves (2x2 of 64x64),
// BK=32, global_load_lds staging (linear LDS dest) with a 3-bit XOR source
// pre-swizzle so fragment ds_read_b128 is bank-conflict-free.
// Swizzle (involution on byte addr): b4^=b7, b5^=b8, b6^=b9.
template <bool F32OUT>
__global__ __launch_bounds__(256) void k_gemm(const unsigned short* __restrict__ A,
                                              const unsigned short* __restrict__ Bt,
                                              const float* __restrict__ bias,
                                              void* __restrict__ Cout,
                                              int M, int N, int K) {
  __shared__ unsigned short As[128 * 32];
  __shared__ unsigned short Bs[128 * 32];
  const int tid = threadIdx.x;
  const int lane = tid & 63, wid = tid >> 6;
  const int wr = wid >> 1, wc = wid & 1;
  const int g = lane >> 4, li = lane & 15;
  const int m0 = blockIdx.y * 128, n0 = blockIdx.x * 128;

  f32x4 acc[4][4] = {};

  const int nkt = K >> 5;
  // staging geometry (per global_load_lds, linear dest = chunk*1024 + lane*16)
  const int srow_in_chunk = lane >> 2;     // 0..15
  const int skp = lane & 3;                // physical k-slot

  auto stage = [&](int kt) {
#pragma unroll
    for (int half = 0; half < 2; ++half) {
      int chunk = wid * 2 + half;                       // 0..7
      int row_p = chunk * 16 + srow_in_chunk;           // physical LDS row
      int row_l = row_p ^ ((row_p >> 3) & 1);           // logical row  (b6^=b9)
      int ks_l  = skp ^ ((row_p >> 1) & 3);             // logical slot (b4,5^=b7,8)
      const unsigned short* ga = A  + (size_t)(m0 + row_l) * K + kt * 32 + ks_l * 8;
      const unsigned short* gb = Bt + (size_t)(n0 + row_l) * K + kt * 32 + ks_l * 8;
      gload_lds16(ga, &As[chunk * 512]);
      gload_lds16(gb, &Bs[chunk * 512]);
    }
  };

  stage(0);
  for (int kt = 0; kt < nkt; ++kt) {
    __syncthreads();                       // drains vmcnt for global_load_lds
    bf16x8 af[4], bfr[4];
#pragma unroll
    for (int mi = 0; mi < 4; ++mi) {
      int r = wr * 64 + mi * 16 + li;
      int rr = r ^ ((r >> 3) & 1);
      int ks = g ^ ((r >> 1) & 3);
      af[mi] = *(const bf16x8*)&As[rr * 32 + (ks << 3)];
    }
#pragma unroll
    for (int ni = 0; ni < 4; ++ni) {
      int r = wc * 64 + ni * 16 + li;
      int rr = r ^ ((r >> 3) & 1);
      int ks = g ^ ((r >> 1) & 3);
      bfr[ni] = *(const bf16x8*)&Bs[rr * 32 + (ks << 3)];
    }
#pragma unroll
    for (int mi = 0; mi < 4; ++mi)
#pragma unroll
      for (int ni = 0; ni < 4; ++ni)
        acc[mi][ni] = __builtin_amdgcn_mfma_f32_16x16x32_bf16(af[mi], bfr[ni],
                                                              acc[mi][ni], 0, 0, 0);
    if (kt + 1 < nkt) {
      __syncthreads();                     // all reads of this tile done
      stage(kt + 1);
    }
  }

  // epilogue: C/D layout col = li, row = g*4+reg  (HW-verified)
  float bv[4];
#pragma unroll
  for (int ni = 0; ni < 4; ++ni) bv[ni] = bias[n0 + wc * 64 + ni * 16 + li];
#pragma unroll
  for (int mi = 0; mi < 4; ++mi) {
#pragma unroll
    for (int ni = 0; ni < 4; ++ni) {
      const int col = n0 + wc * 64 + ni * 16 + li;
#pragma unroll
      for (int reg = 0; reg < 4; ++reg) {
        const int row = m0 + wr * 64 + mi * 16 + g * 4 + reg;
        float v = acc[mi][ni][reg] + bv[ni];
        if (F32OUT) ((float*)Cout)[(size_t)row * N + col] = v;
        else ((unsigned short*)Cout)[(size_t)row * N + col] = f2bf(v);
      }
    }
  }
}

// ------------------------ windowed flash attention -------------------------
// qkv: (4096, 3072) bf16 rows = [Q|K|V], each 16 heads x 64.
// Block = one (b,h,q-tile of 64). 4 waves x 16 q-rows. 5 key-tiles of 64:
// tile 0 (j0=q0-256) masked c>=r, tiles 1..3 unmasked, tile 4 (j0=q0) causal.
__global__ __launch_bounds__(256) void k_attn(const unsigned short* __restrict__ qkv,
                                              unsigned short* __restrict__ attn) {
  // stride 88 elems (176B): 16B-aligned rows, conflict-free stride for b128 reads
  __shared__ unsigned short Qs[64 * 88];
  __shared__ unsigned short Ks[64 * 88];
  __shared__ unsigned short Vs[64 * 88];   // V^T: [d][key ^ ((d>>3)<<3)]
  __shared__ unsigned short Ps[64 * 88];   // wave-private 16-row regions
  const int tid = threadIdx.x, lane = tid & 63, wid = tid >> 6;
  const int g = lane >> 4, li = lane & 15;
  const int bh = blockIdx.y, b = bh >> 4, h = bh & 15;
  const int q0 = blockIdx.x * 64;
  const size_t rs = 3072;
  const unsigned short* base = qkv + (size_t)b * 2048 * rs + h * 64;

  // ---- stage Q tile (64x64) ----
#pragma unroll
  for (int rep = 0; rep < 2; ++rep) {
    int idx = rep * 256 + tid;
    int row = idx >> 3, slot = idx & 7;
    u32x4 v = *(const u32x4*)(base + (size_t)(q0 + row) * rs + slot * 8);
    *(u32x4*)&Qs[row * 88 + slot * 8] = v;
  }
  __syncthreads();
  const int qrow = wid * 16 + li;
  const bf16x8 qf0 = *(const bf16x8*)&Qs[qrow * 88 + (g << 3)];
  const bf16x8 qf1 = *(const bf16x8*)&Qs[qrow * 88 + 32 + (g << 3)];

  f32x4 o[4] = {};
  float m_run[4] = {-3e30f, -3e30f, -3e30f, -3e30f};
  float l_part[4] = {0.f, 0.f, 0.f, 0.f};

  for (int t = 0; t < 5; ++t) {
    const int j0 = q0 - 256 + t * 64;
    if (j0 < 0) continue;                  // uniform across block
    __syncthreads();                       // prev tile's reads done
    // ---- stage K (row-major) and V (transposed + key-XOR swizzle) ----
#pragma unroll
    for (int rep = 0; rep < 2; ++rep) {
      int idx = rep * 256 + tid;
      int row = idx >> 3, slot = idx & 7;
      const unsigned short* gk = base + (size_t)(j0 + row) * rs + 1024 + slot * 8;
      *(u32x4*)&Ks[row * 88 + slot * 8] = *(const u32x4*)gk;
      u32x4 vv = *(const u32x4*)(base + (size_t)(j0 + row) * rs + 2048 + slot * 8);
      int colsw = row ^ (slot << 3);       // key ^ ((d>>3)<<3), d = slot*8+jj
#pragma unroll
      for (int jj = 0; jj < 8; ++jj) {
        unsigned short e = (unsigned short)(vv[jj >> 1] >> ((jj & 1) * 16));
        Vs[(slot * 8 + jj) * 88 + colsw] = e;
      }
    }
    __syncthreads();

    // ---- S = (Q K^T) * scale, masked ----
    f32x4 s[4];
#pragma unroll
    for (int ni = 0; ni < 4; ++ni) {
      int krow = ni * 16 + li;
      bf16x8 kf0 = *(const bf16x8*)&Ks[krow * 88 + (g << 3)];
      bf16x8 kf1 = *(const bf16x8*)&Ks[krow * 88 + 32 + (g << 3)];
      f32x4 z = {};
      z = __builtin_amdgcn_mfma_f32_16x16x32_bf16(qf0, kf0, z, 0, 0, 0);
      z = __builtin_amdgcn_mfma_f32_16x16x32_bf16(qf1, kf1, z, 0, 0, 0);
      s[ni] = z;
    }
    const int rt = wid * 16 + g * 4;       // + reg = q row in tile
#pragma unroll
    for (int ni = 0; ni < 4; ++ni) {
      int ct = ni * 16 + li;               // key col in tile
#pragma unroll
      for (int reg = 0; reg < 4; ++reg) {
        float sv = s[ni][reg] * 0.125f;
        if (t == 4 && ct > rt + reg) sv = -3e30f;   // causal
        if (t == 0 && ct < rt + reg) sv = -3e30f;   // window lower bound
        s[ni][reg] = sv;
      }
    }
    // ---- online softmax ----
    float alpha[4];
#pragma unroll
    for (int reg = 0; reg < 4; ++reg) {
      float mx = fmaxf(fmaxf(s[0][reg], s[1][reg]), fmaxf(s[2][reg], s[3][reg]));
      mx = fmaxf(mx, __shfl_xor(mx, 1, 64));
      mx = fmaxf(mx, __shfl_xor(mx, 2, 64));
      mx = fmaxf(mx, __shfl_xor(mx, 4, 64));
      mx = fmaxf(mx, __shfl_xor(mx, 8, 64));
      float mnew = fmaxf(m_run[reg], mx);
      alpha[reg] = __expf(m_run[reg] - mnew);
      m_run[reg] = mnew;
    }
#pragma unroll
    for (int reg = 0; reg < 4; ++reg) {
      float ps = 0.f;
#pragma unroll
      for (int ni = 0; ni < 4; ++ni) {
        float p = __expf(s[ni][reg] - m_run[reg]);
        ps += p;
        Ps[(wid * 16 + g * 4 + reg) * 88 + ni * 16 + li] = f2bf(p);
      }
      l_part[reg] = l_part[reg] * alpha[reg] + ps;
#pragma unroll
      for (int ni = 0; ni < 4; ++ni) o[ni][reg] *= alpha[reg];
    }
    // wave-private P round-trip: explicit wait + sched fence (rule #18)
    asm volatile("s_waitcnt lgkmcnt(0)" ::: "memory");
    __builtin_amdgcn_sched_barrier(0);
    const bf16x8 pf0 = *(const bf16x8*)&Ps[(wid * 16 + li) * 88 + (g << 3)];
    const bf16x8 pf1 = *(const bf16x8*)&Ps[(wid * 16 + li) * 88 + 32 + (g << 3)];
#pragma unroll
    for (int ni = 0; ni < 4; ++ni) {
      int drow = ni * 16 + li;
      int sw = drow >> 3;
      bf16x8 vf0 = *(const bf16x8*)&Vs[drow * 88 + (((g) ^ sw) << 3)];
      bf16x8 vf1 = *(const bf16x8*)&Vs[drow * 88 + (((g + 4) ^ sw) << 3)];
      o[ni] = __builtin_amdgcn_mfma_f32_16x16x32_bf16(pf0, vf0, o[ni], 0, 0, 0);
      o[ni] = __builtin_amdgcn_mfma_f32_16x16x32_bf16(pf1, vf1, o[ni], 0, 0, 0);
    }
  }

  // ---- normalize + store (attn layout (B*S, 1024) bf16) ----
  float inv[4];
#pragma unroll
  for (int reg = 0; reg < 4; ++reg) {
    float L = l_part[reg];
    L += __shfl_xor(L, 1, 64);
    L += __shfl_xor(L, 2, 64);
    L += __shfl_xor(L, 4, 64);
    L += __shfl_xor(L, 8, 64);
    inv[reg] = 1.f / L;
  }
#pragma unroll
  for (int ni = 0; ni < 4; ++ni) {
#pragma unroll
    for (int reg = 0; reg < 4; ++reg) {
      size_t row = (size_t)b * 2048 + q0 + wid * 16 + g * 4 + reg;
      attn[row * 1024 + h * 64 + ni * 16 + li] = f2bf(o[ni][reg] * inv[reg]);
    }
  }
}

// ---------------------------------------------------------------------------
extern "C" void kernel_launch(void* const* d_in, const int* in_sizes, int n_in,
                              void* d_out, int out_size, void* d_ws, size_t ws_size,
                              hipStream_t stream) {
  const float* x    = (const float*)d_in[0];   // (4096, 1024)
  const float* Wqkv = (const float*)d_in[1];   // (1024, 3072)
  const float* bqkv = (const float*)d_in[2];   // (3072)
  const float* Wout = (const float*)d_in[3];   // (1024, 1024)
  const float* bout = (const float*)d_in[4];   // (1024)
  float* out = (float*)d_out;                  // (4096, 1024)

  uint8_t* ws = (uint8_t*)d_ws;
  unsigned short* xb    = (unsigned short*)(ws);              //  8.0 MB x bf16
  unsigned short* wqT   = (unsigned short*)(ws +  8388608);   //  6.0 MB Wqkv^T
  unsigned short* woT   = (unsigned short*)(ws + 14680064);   //  2.0 MB Wout^T
  unsigned short* qkvb  = (unsigned short*)(ws + 16777216);   // 24.0 MB qkv
  unsigned short* attnb = (unsigned short*)(ws + 41943040);   //  8.0 MB attn out

  k_f32_to_bf16<<<4096, 256, 0, stream>>>(x, xb, 1048576);
  k_transpose_w<<<dim3(3072 / 32, 1024 / 32), dim3(32, 8), 0, stream>>>(Wqkv, wqT, 1024, 3072);
  k_transpose_w<<<dim3(1024 / 32, 1024 / 32), dim3(32, 8), 0, stream>>>(Wout, woT, 1024, 1024);
  k_gemm<false><<<dim3(3072 / 128, 4096 / 128), 256, 0, stream>>>(xb, wqT, bqkv, qkvb,
                                                                  4096, 3072, 1024);
  k_attn<<<dim3(2048 / 64, 32), 256, 0, stream>>>(qkvb, attnb);
  k_gemm<true><<<dim3(1024 / 128, 4096 / 128), 256, 0, stream>>>(attnb, woT, bout, out,
                                                                 4096, 1024, 1024);
}